// Round 1
// baseline (133.274 us; speedup 1.0000x reference)
//
#include <hip/hip_runtime.h>

typedef unsigned short u16;
typedef short bf16x8 __attribute__((ext_vector_type(8)));
typedef float f32x4 __attribute__((ext_vector_type(4)));

#define BB 8
#define CC 768
#define NN 256
#define HH 12
#define DD 64
#define BCN 196608       // C*N per batch
#define SCALE 0.125f
#define LDP 72           // LDS pitch (u16): 144B rows, 16B-aligned, 2-way banks only

__device__ __forceinline__ u16 f2b(float f) {
    union { float f; unsigned int i; } v; v.f = f;
    unsigned int r = v.i + 0x7FFFu + ((v.i >> 16) & 1u);
    return (u16)(r >> 16);
}

// one 64x64x64 MFMA macro-step (4 waves, each 32x32, K=64 in two k-halves)
#define MFMA8(ASP, BSP, ACC)                                                              \
    _Pragma("unroll")                                                                     \
    for (int kk = 0; kk < 2; ++kk) {                                                      \
        bf16x8 a0 = *reinterpret_cast<bf16x8*>((ASP) + (wm + tx) * LDP + kk * 32 + q * 8);\
        bf16x8 a1 = *reinterpret_cast<bf16x8*>((ASP) + (wm + 16 + tx) * LDP + kk * 32 + q * 8);\
        bf16x8 b0 = *reinterpret_cast<bf16x8*>((BSP) + (wn + tx) * LDP + kk * 32 + q * 8);\
        bf16x8 b1 = *reinterpret_cast<bf16x8*>((BSP) + (wn + 16 + tx) * LDP + kk * 32 + q * 8);\
        ACC[0][0] = __builtin_amdgcn_mfma_f32_16x16x32_bf16(a0, b0, ACC[0][0], 0, 0, 0);  \
        ACC[0][1] = __builtin_amdgcn_mfma_f32_16x16x32_bf16(a0, b1, ACC[0][1], 0, 0, 0);  \
        ACC[1][0] = __builtin_amdgcn_mfma_f32_16x16x32_bf16(a1, b0, ACC[1][0], 0, 0, 0);  \
        ACC[1][1] = __builtin_amdgcn_mfma_f32_16x16x32_bf16(a1, b1, ACC[1][1], 0, 0, 0);  \
    }

// ---------------------------------------------------------------------------
// Stage 1 (fused proj+gram): block = (h, n-chunk, b).
//   cp_h[dd][n] = sum_c Wp[dd*12+h][c] * cross[c][n0+n]        (12 K-iters,
//   reg-prefetch pipelined), then
//   G[dc][dd] += SCALE * sum_n (cp_h[dd][n]+bp) * cross[dc*12+h][n0+n]
// cp is NEVER materialized to HBM. G pre-zeroed via hipMemsetAsync.
// ---------------------------------------------------------------------------
__global__ __launch_bounds__(256) void k_pg(
    const float* __restrict__ Wp, const float* __restrict__ cross,
    const float* __restrict__ bp, float* __restrict__ G)
{
    __shared__ __align__(16) u16 As[64 * LDP];
    __shared__ __align__(16) u16 Bs[64 * LDP];
    __shared__ __align__(16) float T[64][68];
    const int h  = blockIdx.x;          // 0..11
    const int n0 = blockIdx.y * 64;     // 4 chunks
    const int b  = blockIdx.z;
    const int t = threadIdx.x;
    const int lane = t & 63, wave = t >> 6;
    const int q = lane >> 4, tx = lane & 15;
    const int wm = (wave & 1) * 32, wn = (wave >> 1) * 32;
    const int r4 = t >> 2, cq = t & 3;
    const float* crb = cross + b * BCN;
    const float* wrow = Wp + (r4 * HH + h) * CC;   // Wp_h row dd=r4 (stride-12 rows)

    f32x4 acc[2][2] = {};
    float4 ra[4], rc[4];
    // prologue: iter-0 tiles -> regs
    #pragma unroll
    for (int u = 0; u < 4; ++u) {
        const int cl = (cq + 4 * u) * 4;
        ra[u] = *reinterpret_cast<const float4*>(wrow + cl);
        rc[u] = *reinterpret_cast<const float4*>(crb + r4 * NN + n0 + cl);
    }
    for (int it = 0; it < 12; ++it) {
        if (it > 0) __syncthreads();          // prev mfma readers of As/Bs/T done
        {   // regs -> As (cvt) and T (f32)
            u16* dstA = As + r4 * LDP;
            #pragma unroll
            for (int u = 0; u < 4; ++u) {
                const int cl = (cq + 4 * u) * 4;
                ushort4 w; w.x = f2b(ra[u].x); w.y = f2b(ra[u].y);
                w.z = f2b(ra[u].z); w.w = f2b(ra[u].w);
                *reinterpret_cast<ushort4*>(dstA + cl) = w;
                T[r4][cl + 0] = rc[u].x; T[r4][cl + 1] = rc[u].y;
                T[r4][cl + 2] = rc[u].z; T[r4][cl + 3] = rc[u].w;
            }
        }
        if (it < 11) {   // issue next-iter global loads; latency hides under transpose+mfma
            const int c0 = (it + 1) * 64;
            #pragma unroll
            for (int u = 0; u < 4; ++u) {
                const int cl = (cq + 4 * u) * 4;
                ra[u] = *reinterpret_cast<const float4*>(wrow + c0 + cl);
                rc[u] = *reinterpret_cast<const float4*>(crb + (c0 + r4) * NN + n0 + cl);
            }
        }
        __syncthreads();
        {   // Bs[n][c] = cvt(T[c][n])  (transpose; col reads 2-way = free)
            const int nn = t >> 2, dq = t & 3;
            u16* dst = Bs + nn * LDP;
            #pragma unroll
            for (int u = 0; u < 4; ++u) {
                const int c4 = (dq + 4 * u) * 4;
                ushort4 w;
                w.x = f2b(T[c4 + 0][nn]); w.y = f2b(T[c4 + 1][nn]);
                w.z = f2b(T[c4 + 2][nn]); w.w = f2b(T[c4 + 3][nn]);
                *reinterpret_cast<ushort4*>(dst + c4) = w;
            }
        }
        __syncthreads();
        MFMA8(As, Bs, acc)
    }
    __syncthreads();                         // protect As/Bs reuse for gram
    // gram B operand: cross_h rows dc -> regs (issued early, hides under As2 stores)
    float4 rg[4];
    #pragma unroll
    for (int u = 0; u < 4; ++u)
        rg[u] = *reinterpret_cast<const float4*>(crb + (r4 * HH + h) * NN + n0 + (cq + 4 * u) * 4);
    // As2[dd][n] = bf16(cp_partial + bias)
    #pragma unroll
    for (int i = 0; i < 2; ++i)
        #pragma unroll
        for (int r = 0; r < 4; ++r) {
            const int ddl = wm + i * 16 + q * 4 + r;
            const float bias = bp[ddl * HH + h];
            #pragma unroll
            for (int j = 0; j < 2; ++j)
                As[ddl * LDP + wn + j * 16 + tx] = f2b(acc[i][j][r] + bias);
        }
    {   // Bs2[dc][n] = bf16(cross_h)
        u16* dst = Bs + r4 * LDP;
        #pragma unroll
        for (int u = 0; u < 4; ++u) {
            const int cl = (cq + 4 * u) * 4;
            ushort4 w; w.x = f2b(rg[u].x); w.y = f2b(rg[u].y);
            w.z = f2b(rg[u].z); w.w = f2b(rg[u].w);
            *reinterpret_cast<ushort4*>(dst + cl) = w;
        }
    }
    __syncthreads();
    f32x4 g[2][2] = {};
    MFMA8(As, Bs, g)
    float* Gb = G + b * 4096;
    #pragma unroll
    for (int i = 0; i < 2; ++i)
        #pragma unroll
        for (int j = 0; j < 2; ++j)
            #pragma unroll
            for (int r = 0; r < 4; ++r) {
                const int dd = wm + i * 16 + q * 4 + r;   // cp-side (G col)
                const int dc = wn + j * 16 + tx;          // cross-side (G row)
                atomicAdd(Gb + dc * DD + dd, g[i][j][r] * SCALE);
            }
}

// ---------------------------------------------------------------------------
// Stage 2: U[b][m][dd] = sum_d xT[m][d]*G[dd][d].  Single K-iter; unchanged.
// ---------------------------------------------------------------------------
__global__ __launch_bounds__(256) void k_xm(
    const float* __restrict__ x, const float* __restrict__ G, u16* __restrict__ U)
{
    __shared__ __align__(16) u16 As[64 * LDP];
    __shared__ __align__(16) u16 Bs[64 * LDP];
    __shared__ __align__(16) float T[64][68];
    const int m0 = blockIdx.x * 64;
    const int b  = blockIdx.y;
    const int h   = m0 >> 8;
    const int nn0 = m0 & 255;
    const int t = threadIdx.x;
    const int lane = t & 63, wave = t >> 6;
    const int q = lane >> 4, tx = lane & 15;
    const int wm = (wave & 1) * 32, wn = (wave >> 1) * 32;
    const float* xb = x + b * BCN;
    const float* Gb = G + b * 4096;
    f32x4 acc[2][2] = {};
    {   // T[d][nl] = x[(d*12+h)*256 + nn0+nl]
        const int d = t >> 2, fq = t & 3;
        const float* src = xb + (d * HH + h) * NN + nn0;
        #pragma unroll
        for (int u = 0; u < 4; ++u) {
            const int nl = (fq + 4 * u) * 4;
            float4 v = *reinterpret_cast<const float4*>(src + nl);
            T[d][nl + 0] = v.x; T[d][nl + 1] = v.y; T[d][nl + 2] = v.z; T[d][nl + 3] = v.w;
        }
    }
    {   // Bs[dd][d] = cvt(G[dd][d])
        const int r = t >> 2, cq = t & 3;
        const float* src = Gb + r * DD;
        u16* dst = Bs + r * LDP;
        #pragma unroll
        for (int u = 0; u < 4; ++u) {
            const int cl = (cq + 4 * u) * 4;
            float4 v = *reinterpret_cast<const float4*>(src + cl);
            ushort4 w; w.x = f2b(v.x); w.y = f2b(v.y); w.z = f2b(v.z); w.w = f2b(v.w);
            *reinterpret_cast<ushort4*>(dst + cl) = w;
        }
    }
    __syncthreads();
    {   // As[m_local][d] = cvt(T[d][m_local])
        const int nn = t >> 2, dq = t & 3;
        u16* dst = As + nn * LDP;
        #pragma unroll
        for (int u = 0; u < 4; ++u) {
            const int d4 = (dq + 4 * u) * 4;
            ushort4 w;
            w.x = f2b(T[d4 + 0][nn]); w.y = f2b(T[d4 + 1][nn]);
            w.z = f2b(T[d4 + 2][nn]); w.w = f2b(T[d4 + 3][nn]);
            *reinterpret_cast<ushort4*>(dst + d4) = w;
        }
    }
    __syncthreads();
    MFMA8(As, Bs, acc)
    u16* Ub = U + b * BCN;
    #pragma unroll
    for (int i = 0; i < 2; ++i)
        #pragma unroll
        for (int j = 0; j < 2; ++j)
            #pragma unroll
            for (int r = 0; r < 4; ++r) {
                const int m  = m0 + wm + i * 16 + q * 4 + r;
                const int dd = wn + j * 16 + tx;
                Ub[m * DD + dd] = f2b(acc[i][j][r]);
            }
}

// ---------------------------------------------------------------------------
// Stage 3: out[b,o,n] = x[b,o,n] + bd[o] + sum_k Wd[o,k]*U2[n,k]
// Double-buffered LDS + register prefetch: one barrier per K-iter, global
// loads in flight across the MFMAs (latency-exposed regime, ~1.5 blocks/CU).
// ---------------------------------------------------------------------------
__global__ __launch_bounds__(256) void k_dep(
    const float* __restrict__ Wd, const u16* __restrict__ U,
    const float* __restrict__ bd, const float* __restrict__ x, float* __restrict__ out)
{
    __shared__ __align__(16) u16 As[2][64 * LDP];
    __shared__ __align__(16) u16 Bs[2][64 * LDP];
    const int n0 = blockIdx.x * 64;
    const int o0 = blockIdx.y * 64;
    const int b  = blockIdx.z;
    const int t = threadIdx.x;
    const int lane = t & 63, wave = t >> 6;
    const int q = lane >> 4, tx = lane & 15;
    const int wm = (wave & 1) * 32, wn = (wave >> 1) * 32;
    const int r4 = t >> 2, cq = t & 3;
    const int r8 = t >> 3, ch = (t & 7) * 8;
    const u16* Ub = U + b * BCN;
    float4 ra[4]; uint4 rb[2];

    auto loadit = [&](int it) {
        const int c0 = it * 64;
        const float* srcA = Wd + (o0 + r4) * CC + c0;
        #pragma unroll
        for (int u = 0; u < 4; ++u)
            ra[u] = *reinterpret_cast<const float4*>(srcA + (cq + 4 * u) * 4);
        rb[0] = *reinterpret_cast<const uint4*>(Ub + (n0 + r8) * CC + c0 + ch);
        rb[1] = *reinterpret_cast<const uint4*>(Ub + (n0 + r8 + 32) * CC + c0 + ch);
    };
    auto storeit = [&](int buf) {
        u16* dst = As[buf] + r4 * LDP;
        #pragma unroll
        for (int u = 0; u < 4; ++u) {
            const int cl = (cq + 4 * u) * 4;
            ushort4 w; w.x = f2b(ra[u].x); w.y = f2b(ra[u].y);
            w.z = f2b(ra[u].z); w.w = f2b(ra[u].w);
            *reinterpret_cast<ushort4*>(dst + cl) = w;
        }
        *reinterpret_cast<uint4*>(Bs[buf] + r8 * LDP + ch) = rb[0];
        *reinterpret_cast<uint4*>(Bs[buf] + (r8 + 32) * LDP + ch) = rb[1];
    };

    f32x4 acc[2][2] = {};
    loadit(0);
    storeit(0);
    #pragma unroll 2
    for (int it = 0; it < 12; ++it) {
        const int cur = it & 1;
        if (it < 11) loadit(it + 1);       // in flight across barrier + MFMAs
        __syncthreads();                   // LDS[cur] visible; prev readers of cur^1 done
        MFMA8(As[cur], Bs[cur], acc)
        if (it < 11) storeit(cur ^ 1);     // vmcnt wait lands after the MFMAs
    }
    #pragma unroll
    for (int i = 0; i < 2; ++i)
        #pragma unroll
        for (int j = 0; j < 2; ++j)
            #pragma unroll
            for (int r = 0; r < 4; ++r) {
                const int o = o0 + wm + i * 16 + q * 4 + r;
                const int n = n0 + wn + j * 16 + tx;
                const int idx = b * BCN + o * NN + n;
                out[idx] = acc[i][j][r] + bd[o] + x[idx];
            }
}

extern "C" void kernel_launch(void* const* d_in, const int* in_sizes, int n_in,
                              void* d_out, int out_size, void* d_ws, size_t ws_size,
                              hipStream_t stream) {
    const float* x_ori = (const float*)d_in[0];
    const float* cross = (const float*)d_in[1];
    const float* Wp    = (const float*)d_in[2];
    const float* bp    = (const float*)d_in[3];
    const float* Wd    = (const float*)d_in[4];
    const float* bd    = (const float*)d_in[5];
    float* out = (float*)d_out;

    // ws: [0, 3,145,728): U bf16 [8][3072][64]
    //     [3,145,728, +131,072): G f32 [8][64][64] (memset-zeroed, atomic-accumulated)
    u16*   U  = (u16*)d_ws;
    float* G  = (float*)((char*)d_ws + (size_t)BB * BCN * sizeof(u16));

    hipMemsetAsync(G, 0, (size_t)BB * DD * DD * sizeof(float), stream);
    k_pg <<<dim3(HH, 4, BB), 256, 0, stream>>>(Wp, cross, bp, G);
    k_xm <<<dim3(48, BB), 256, 0, stream>>>(x_ori, G, U);
    k_dep<<<dim3(4, 12, BB), 256, 0, stream>>>(Wd, U, bd, x_ori, out);
}